// Round 3
// baseline (324.922 us; speedup 1.0000x reference)
//
#include <hip/hip_runtime.h>

typedef unsigned short u16;
typedef unsigned int u32;
typedef __attribute__((ext_vector_type(8))) short bf16x8;   // 8 bf16 = 4 VGPRs
typedef __attribute__((ext_vector_type(4))) float f32x4;

// ---- ws layout (planar path) ----
// xp bf16 [8][66][66][512] halo-padded NHWC : 35,684,352 B at 0
// yb: 8 u16 lead pad + 2048 chunks x 16776 u16 + 16 u16 trail = 68,714,544 B
//   per (img,o) chunk: plane0 (65x66) @0 sz4296 | plane1 (65x64) @4296 sz4160
//                      plane2 (64x66) @8456 sz4224 | plane3 (64x64) @12680 sz4096
// Hy bf16 [9][256][512] = 2,359,296 B
#define XP_BYTES 35684352
#define YB_BYTES 68714544
#define HY_OFF   (XP_BYTES + YB_BYTES)          // 104,398,896
#define WS_NEED  ((size_t)HY_OFF + 2359296)     // 106,758,192
#define CS 16776                                 // chunk stride (u16)

__device__ inline u16 f2bf(float f) {
  union { float f; unsigned u; } v; v.f = f;
  unsigned r = v.u + 0x7fffu + ((v.u >> 16) & 1u);
  return (u16)(r >> 16);
}

__device__ inline void gl_lds16(const u16* g, u16* l) {
  __builtin_amdgcn_global_load_lds(
      (const __attribute__((address_space(1))) unsigned int*)g,
      (__attribute__((address_space(3))) unsigned int*)l, 16, 0, 0);
}

// ---------------- x prep: f32 NCHW -> bf16 NHWC with 1-px zero halo (self-zeroing) ----------
__global__ void xprep(const float* __restrict__ x, u16* __restrict__ xp) {
  __shared__ float tile[64 * 65];
  int bid = blockIdx.x;
  int cc = bid & 7, h = (bid >> 3) & 63, n = bid >> 9;
  int c0 = cc * 64;
  int t = threadIdx.x;
  const float* xb = x + ((size_t)(n * 512 + c0) * 64 + h) * 64;
  for (int r = 0; r < 16; ++r) {
    int flat = r * 256 + t;
    int ci = flat >> 6, w = flat & 63;
    tile[w * 65 + ci] = xb[(size_t)ci * 4096 + w];
  }
  __syncthreads();
  u16* xpb = xp + ((size_t)(n * 66 + h + 1) * 66 + 1) * 512 + c0;
  for (int r = 0; r < 8; ++r) {
    int flat = r * 256 + t;
    int pr = flat & 31;
    int w = flat >> 5;
    int ci = pr * 2;
    float v0 = tile[w * 65 + ci], v1 = tile[w * 65 + ci + 1];
    unsigned pk = (unsigned)f2bf(v0) | ((unsigned)f2bf(v1) << 16);
    *(unsigned*)(xpb + (size_t)w * 512 + ci) = pk;
  }
  u16* rowbase = xp + ((size_t)(n * 66 + h + 1) * 66) * 512 + c0;
  if (t < 32) *(u32*)(rowbase + 2 * t) = 0u;
  else if (t < 64) *(u32*)(rowbase + (size_t)65 * 512 + 2 * (t - 32)) = 0u;
  if (h == 0) {
    u16* r0 = xp + ((size_t)(n * 66) * 66) * 512 + c0;
    for (int j = t; j < 2112; j += 256) {
      int col = j >> 5, wi = j & 31;
      *(u32*)(r0 + (size_t)col * 512 + 2 * wi) = 0u;
    }
  }
  if (h == 63) {
    u16* r65 = xp + ((size_t)(n * 66 + 65) * 66) * 512 + c0;
    for (int j = t; j < 2112; j += 256) {
      int col = j >> 5, wi = j & 31;
      *(u32*)(r65 + (size_t)col * 512 + 2 * wi) = 0u;
    }
  }
}

// ---------------- weight prep: modulate+demod, 9 conv-transpose tap planes ----------------
__global__ void wprep9(const float* __restrict__ w, u16* __restrict__ Hy) {
  __shared__ float wl[4608];
  __shared__ float red[256];
  int o = blockIdx.x, t = threadIdx.x;
  const float* wo = w + (size_t)o * 4608;
  float s = 0.f;
  for (int j = t; j < 4608; j += 256) { float v = wo[j]; wl[j] = v; s += v * v; }
  red[t] = s;
  __syncthreads();
  for (int st = 128; st; st >>= 1) { if (t < st) red[t] += red[t + st]; __syncthreads(); }
  float demod = rsqrtf(red[0] * (1.0f / 4608.0f) + 1e-6f);
  float scale = demod * 0.014731391274719739f;
  const int DY[9] = {0, 2, 0, 2, 0, 2, 1, 1, 1};
  const int DX[9] = {0, 0, 2, 2, 1, 1, 0, 2, 1};
  for (int i = t; i < 512; i += 256) {
#pragma unroll
    for (int pl = 0; pl < 9; ++pl) {
      float g = wl[i * 9 + DY[pl] * 3 + DX[pl]] * scale;
      Hy[(size_t)pl * 131072 + (size_t)o * 512 + i] = f2bf(g);
    }
  }
}

// ---------------- pass 1: conv-transpose y — BM256 x BN128, BK=32, 2 blocks/CU ----------
// 512 thr / 8 waves (2M x 4N); per-wave out 128m x 32o; 2 K-tiles per iter, 6 phases.
// LDS 48KiB: buf c at c*12288 u16: A [0,8192) (256r x 32ch), B [8192,12288) (128r x 32ch).
// XOR swizzle: LDS(r, slot) = G(r, slot ^ (r&3)) at 16B chunks (4 chunks/row); staged via
// pre-swizzled global source (gch = (t&3)^(rho&3)), read back slot = grp ^ (r&3).
// Phase plan (tiles t0=2it in buf0, t0+1 in buf1); stage issues: A=2x8KB halves, B=1x8KB:
//  p1 rd A-mi0,B-ni0 b0 | st A-h0(t+1)->b1 | q(0,0)
//  p2 rd B-ni1 b0       | st A-h1(t+1)->b1 | q(0,1)
//  p3 rd A-mi1 b0       | st B(t+2)->b0    | q(1,1)+q(1,0) ; WAITV1 [V0 last iter]
//  p4-p6 mirror on b1: st A(t+2)->b0 (p4,p5), B(t+3)->b1 (p6); WAITV1 at p6
// vmcnt ledger (loads/thread): prologue B(t0)1+A(t0)2+B(t1)1=4 -> WAITV1 leaves B(t1).
//  p3: 1+3 issued=4 -> WAITV1 retires B(t1)+A(t1) (needed p4), leaves B(t2).
//  p6: retires B(t2)+A(t2) (needed next p1), leaves B(t3). Last iter: WAITV0 at p3,
//  p4-6 stage nothing (tile>=NK guard) -> epilogue drained.
// WAR: every stage lands >=1 full barrier-pair after its region's last ds_read completes
//  (bf0/bf1 register-held; reads complete at WAITL before the closing barrier that
//  precedes the stage issue). MFMA pinned after lgkmcnt by sched_barrier(0) (rule #18).
// Occupancy: LDS 48K + VGPR<=128 (launch_bounds 512,4) -> 2 blocks/CU; cross-block
//  overlap (m114) fills the read/barrier segments the lockstep schedule serializes.
#define BARR() __builtin_amdgcn_s_barrier()
#define WAITL() do { asm volatile("s_waitcnt lgkmcnt(0)" ::: "memory"); __builtin_amdgcn_sched_barrier(0); } while (0)
#define WAITV1() do { asm volatile("s_waitcnt vmcnt(1)" ::: "memory"); __builtin_amdgcn_sched_barrier(0); } while (0)
#define WAITV0() do { asm volatile("s_waitcnt vmcnt(0)" ::: "memory"); __builtin_amdgcn_sched_barrier(0); } while (0)

__device__ __forceinline__ void rdA4(const u16* sb, int rbase, int grp, bf16x8 af[4]) {
#pragma unroll
  for (int ti = 0; ti < 4; ++ti) {
    int r = rbase + ti * 16;
    int ch = grp ^ (r & 3);
    af[ti] = *(const bf16x8*)(sb + r * 32 + ch * 8);
  }
}

__device__ __forceinline__ bf16x8 rdB1(const u16* sb, int r, int grp) {
  int ch = grp ^ (r & 3);
  return *(const bf16x8*)(sb + 8192 + r * 32 + ch * 8);
}

template <int MI, int NI>
__device__ __forceinline__ void qmfma4(const bf16x8 af[4], bf16x8 bf,
                                       f32x4 acc[8][2]) {
#pragma unroll
  for (int ti = 0; ti < 4; ++ti)
    acc[MI * 4 + ti][NI] = __builtin_amdgcn_mfma_f32_16x16x32_bf16(
        af[ti], bf, acc[MI * 4 + ti][NI], 0, 0, 0);
}

__device__ __forceinline__ void stA1(const u16* __restrict__ xp, u16* d,
                                     int tile, int NK, u32 a,
                                     u32 adj1, u32 adj2, u32 adj3) {
  if (tile < NK) {
    int tap = tile >> 4;
    u32 ko = (u32)((tile & 15) << 5);
    u32 adj = tap == 0 ? 0u : (tap == 1 ? adj1 : (tap == 2 ? adj2 : adj3));
    gl_lds16(xp + (a - adj + ko), d);
  }
}

__device__ __forceinline__ void stB1(const u16* __restrict__ hb, u16* d,
                                     int tile, int NK, u32 b) {
  if (tile < NK) {
    int tap = tile >> 4;
    u32 ko = (u32)((tile & 15) << 5);
    gl_lds16(hb + (size_t)tap * 131072 + (b + ko), d);
  }
}

__global__ __launch_bounds__(512, 4) void conv_y(const u16* __restrict__ xp,
                                                 const u16* __restrict__ Hy,
                                                 u16* __restrict__ yb) {
  __shared__ __align__(16) u16 su[24576];   // 48 KiB: 2 x (A 8192 u16 + B 4096 u16)

  int bid = blockIdx.x;
  int t = threadIdx.x;
  int wid = t >> 6, lane = t & 63;

  // img -> XCD pinned (8 imgs, 8 XCDs); heavy classes first within each img
  int img = bid & 7;
  int kk = bid >> 3;                       // 0..133
  int mt, oh, Wp, CNT, NTAP, PB, PO, STLIM;
  u32 adj1 = 0, adj2 = 0, adj3 = 0;        // (du*66+dv)*512 per tap (tap0 always 0)
  if (kk < 34)       { int k2 = kk;       mt = k2 >> 1; oh = k2 & 1; Wp = 66; CNT = 4290; NTAP = 4; PB = 0; PO = 0;     STLIM = 4296;
                       adj1 = 33792u; adj2 = 512u; adj3 = 34304u; }
  else if (kk < 68)  { int k2 = kk - 34;  mt = k2 >> 1; oh = k2 & 1; Wp = 64; CNT = 4160; NTAP = 2; PB = 4; PO = 4296;  STLIM = 4160;
                       adj1 = 33792u; }
  else if (kk < 102) { int k2 = kk - 68;  mt = k2 >> 1; oh = k2 & 1; Wp = 66; CNT = 4224; NTAP = 2; PB = 6; PO = 8456;  STLIM = 4224;
                       adj1 = 512u; }
  else               { int k2 = kk - 102; mt = k2 >> 1; oh = k2 & 1; Wp = 64; CNT = 4096; NTAP = 1; PB = 8; PO = 12680; STLIM = 4096; }

  int m0 = mt * 256;
  int o0 = oh * 128;
  int NK = NTAP * 16;                       // K-tiles of 32 ch
  int NITER = NTAP * 8;
  const u16* hb = Hy + (size_t)PB * 131072;

  int wm = wid >> 2, wn = wid & 3;          // 2M x 4N waves: wave = 128m x 32o
  int la = lane & 15, grp = lane >> 4;

  // staging coords: 512 threads cover 128 rows x 4 chunks (16B) per 8KB issue
  int rho = t >> 2;                         // 0..127
  int gch = (t & 3) ^ (rho & 3);            // XOR pre-swizzle on global source

  u32 gA0, gA1, gB;
  {
    int m = m0 + rho;
    if (m > CNT - 1) m = CNT - 1;           // clamp (garbage compute, store-guarded)
    u32 a = (u32)m / (u32)Wp;
    u32 b = (u32)m - a * (u32)Wp;
    gA0 = (u32)(((img * 66 + a + 1) * 66 + (b + 1)) * 512 + gch * 8);
    m = m0 + 128 + rho;
    if (m > CNT - 1) m = CNT - 1;
    a = (u32)m / (u32)Wp;
    b = (u32)m - a * (u32)Wp;
    gA1 = (u32)(((img * 66 + a + 1) * 66 + (b + 1)) * 512 + gch * 8);
    gB = (u32)((o0 + rho) * 512 + gch * 8);
  }
  int ws = wid * 512;                       // per-wave staging slice (1 KiB)

  f32x4 acc[8][2];
#pragma unroll
  for (int i = 0; i < 8; ++i)
#pragma unroll
    for (int j = 0; j < 2; ++j) acc[i][j] = (f32x4){0.f, 0.f, 0.f, 0.f};

  // ---- prologue: B(t0), A(t0) both halves, B(t1); wait tile0, keep B(t1) in flight
  stB1(hb, su + 8192 + ws, 0, NK, gB);
  stA1(xp, su + 0 + ws, 0, NK, gA0, adj1, adj2, adj3);
  stA1(xp, su + 4096 + ws, 0, NK, gA1, adj1, adj2, adj3);
  stB1(hb, su + 20480 + ws, 1, NK, gB);
  WAITV1();
  BARR();

  bf16x8 af[4], bf0, bf1;

#pragma unroll 1
  for (int it = 0; it < NITER; ++it) {
    int t0 = 2 * it;
    bool more = (it + 1 < NITER);

    // ---- p1: buf0 q(0,0) | stage A-h0(t0+1) -> buf1
    rdA4(su, wm * 128 + la, grp, af);
    bf0 = rdB1(su, wn * 32 + la, grp);
    stA1(xp, su + 12288 + ws, t0 + 1, NK, gA0, adj1, adj2, adj3);
    BARR(); WAITL();
    __builtin_amdgcn_s_setprio(1); qmfma4<0, 0>(af, bf0, acc); __builtin_amdgcn_s_setprio(0);
    BARR();
    // ---- p2: q(0,1) | stage A-h1(t0+1) -> buf1
    bf1 = rdB1(su, wn * 32 + 16 + la, grp);
    stA1(xp, su + 16384 + ws, t0 + 1, NK, gA1, adj1, adj2, adj3);
    BARR(); WAITL();
    __builtin_amdgcn_s_setprio(1); qmfma4<0, 1>(af, bf1, acc); __builtin_amdgcn_s_setprio(0);
    BARR();
    // ---- p3: q(1,1)+q(1,0) | stage B(t0+2) -> buf0 | counted vmcnt
    rdA4(su, wm * 128 + 64 + la, grp, af);
    stB1(hb, su + 8192 + ws, t0 + 2, NK, gB);
    BARR(); WAITL();
    __builtin_amdgcn_s_setprio(1);
    qmfma4<1, 1>(af, bf1, acc); qmfma4<1, 0>(af, bf0, acc);
    __builtin_amdgcn_s_setprio(0);
    if (more) { WAITV1(); } else { WAITV0(); }
    BARR();
    // ---- p4: buf1 q(0,0) | stage A-h0(t0+2) -> buf0
    rdA4(su + 12288, wm * 128 + la, grp, af);
    bf0 = rdB1(su + 12288, wn * 32 + la, grp);
    stA1(xp, su + 0 + ws, t0 + 2, NK, gA0, adj1, adj2, adj3);
    BARR(); WAITL();
    __builtin_amdgcn_s_setprio(1); qmfma4<0, 0>(af, bf0, acc); __builtin_amdgcn_s_setprio(0);
    BARR();
    // ---- p5: q(0,1) | stage A-h1(t0+2) -> buf0
    bf1 = rdB1(su + 12288, wn * 32 + 16 + la, grp);
    stA1(xp, su + 4096 + ws, t0 + 2, NK, gA1, adj1, adj2, adj3);
    BARR(); WAITL();
    __builtin_amdgcn_s_setprio(1); qmfma4<0, 1>(af, bf1, acc); __builtin_amdgcn_s_setprio(0);
    BARR();
    // ---- p6: q(1,1)+q(1,0) | stage B(t0+3) -> buf1 | counted vmcnt
    rdA4(su + 12288, wm * 128 + 64 + la, grp, af);
    stB1(hb, su + 20480 + ws, t0 + 3, NK, gB);
    BARR(); WAITL();
    __builtin_amdgcn_s_setprio(1);
    qmfma4<1, 1>(af, bf1, acc); qmfma4<1, 0>(af, bf0, acc);
    __builtin_amdgcn_s_setprio(0);
    if (more) { WAITV1(); }
    BARR();
  }

  // ---- epilogue: two o-half rounds through LDS [64 o][256 m] u16 (32 KiB), XOR chunks
  WAITV0();          // defensive drain (ledger says already 0 here)
  __syncthreads();
  u16* ybp = yb + 8;
#pragma unroll 1
  for (int r = 0; r < 2; ++r) {
    if ((wn >> 1) == r) {
      int base_orl = (wn & 1) * 32;
#pragma unroll
      for (int nj = 0; nj < 2; ++nj) {
        int orl = base_orl + nj * 16 + la;
        int x7 = orl & 7;
#pragma unroll
        for (int mi8 = 0; mi8 < 8; ++mi8)
#pragma unroll
          for (int jp = 0; jp < 2; ++jp) {
            int ml = wm * 128 + mi8 * 16 + grp * 4 + jp * 2;
            u32 pk = (u32)f2bf(acc[mi8][nj][jp * 2]) |
                     ((u32)f2bf(acc[mi8][nj][jp * 2 + 1]) << 16);
            *(u32*)(su + orl * 256 + (((ml >> 3) ^ x7) * 8) + (ml & 7)) = pk;
          }
      }
    }
    __syncthreads();
    {
      int ol = t >> 3, s2 = t & 7;
      int og = o0 + r * 64 + ol;
      size_t gb = (size_t)(img * 256 + og) * CS + PO + m0;
      int x7 = ol & 7;
#pragma unroll
      for (int i = 0; i < 4; ++i) {
        int cidx = s2 * 4 + i;
        int m = cidx * 8;
        if (m0 + m < STLIM)
          *(bf16x8*)(ybp + gb + m) = *(const bf16x8*)(su + ol * 256 + ((cidx ^ x7) * 8));
      }
    }
    if (r == 0) __syncthreads();
  }
}

// ---------------- pass 2: depthwise FIR on planar y; thread = 4p x 8q z block ----------------
// Derivation (R4 bug fixed): z[p][q] = (1/16) sum f1[s]f1[t] y[p+s-1][q+t-1], f1={1,3,3,1}.
// y-phase row 2a+rp: s = 2a+rp-p+1. With a0 = 2*phb-1, hcol index la -> a = a0+la:
//   rp=0: ip0: 3h[1]+h[2] | ip1: h[1]+3h[2] | ip2: 3h[2]+h[3] | ip3: h[2]+3h[3]
//   rp=1: ip0: h[0]+3h[1] | ip1: 3h[1]+h[2] | ip2: h[1]+3h[2] | ip3: 3h[2]+h[3]
// cols with b0 = 4*qh-1, v index lb -> b = b0+lb, e = jq>>1:
//   rq=0: jq=2e: 3v[e+1]+v[e+2] | jq=2e+1: v[e+1]+3v[e+2]
//   rq=1: jq=2e: v[e]+3v[e+1]   | jq=2e+1: 3v[e+1]+v[e+2]
__global__ void fir2(const u16* __restrict__ yb, float* __restrict__ z) {
  int flat = blockIdx.x * 256 + threadIdx.x;
  int qh = flat & 15, phb = (flat >> 4) & 31, o = (flat >> 9) & 255, n = flat >> 17;
  const u16* cb = yb + 8 + (size_t)(n * 256 + o) * CS;
  int a0 = 2 * phb - 1;
  int b0 = 4 * qh - 1;

  float out[4][8];
#pragma unroll
  for (int i = 0; i < 4; ++i)
#pragma unroll
    for (int j = 0; j < 8; ++j) out[i][j] = 0.f;

  const int PO_[4] = {0, 4296, 8456, 12680};
  const int WP_[4] = {66, 64, 66, 64};
  const int HA_[4] = {65, 65, 64, 64};
  const int WB_[4] = {65, 64, 65, 64};

#pragma unroll
  for (int ph = 0; ph < 4; ++ph) {
    int rp = ph >> 1, rq = ph & 1;
    const u16* pb = cb + PO_[ph];
    float hcol[4][8];
#pragma unroll
    for (int la = 0; la < 4; ++la) {
      if (rp == 0 && la == 0) continue;          // row unused for rp=0 (folds at compile time)
      int ag = a0 + la;
      bool rv = (ag >= 0) && (ag < HA_[ph]);
      const u16* rb = pb + (ag * WP_[ph] + b0 - 1);   // even offset; pads keep it in d_ws
      u32 ls[4];
      ls[0] = *(const u32*)(rb);
      ls[1] = *(const u32*)(rb + 2);
      ls[2] = *(const u32*)(rb + 4);
      ls[3] = *(const u32*)(rb + 6);
      float v[6];
#pragma unroll
      for (int lb = 0; lb < 6; ++lb) {
        int jj = lb + 1;                          // rb[jj] = col b0-1+jj = b0+lb
        u32 w16 = (jj & 1) ? (ls[jj >> 1] >> 16) : (ls[jj >> 1] & 0xffffu);
        float fv = __uint_as_float(w16 << 16);
        int bg = b0 + lb;
        bool ok = rv && (bg >= 0) && (bg < WB_[ph]);
        v[lb] = ok ? fv : 0.f;
      }
#pragma unroll
      for (int e = 0; e < 4; ++e) {
        if (rq == 0) {
          hcol[la][2 * e]     = 3.f * v[e + 1] + v[e + 2];
          hcol[la][2 * e + 1] = v[e + 1] + 3.f * v[e + 2];
        } else {
          hcol[la][2 * e]     = v[e] + 3.f * v[e + 1];
          hcol[la][2 * e + 1] = 3.f * v[e + 1] + v[e + 2];
        }
      }
    }
#pragma unroll
    for (int jq = 0; jq < 8; ++jq) {
      if (rp == 0) {
        out[0][jq] += 3.f * hcol[1][jq] + hcol[2][jq];
        out[1][jq] += hcol[1][jq] + 3.f * hcol[2][jq];
        out[2][jq] += 3.f * hcol[2][jq] + hcol[3][jq];
        out[3][jq] += hcol[2][jq] + 3.f * hcol[3][jq];
      } else {
        out[0][jq] += hcol[0][jq] + 3.f * hcol[1][jq];
        out[1][jq] += 3.f * hcol[1][jq] + hcol[2][jq];
        out[2][jq] += hcol[1][jq] + 3.f * hcol[2][jq];
        out[3][jq] += 3.f * hcol[2][jq] + hcol[3][jq];
      }
    }
  }

  float* zb = z + ((size_t)(n * 256 + o) * 128 + phb * 4) * 128 + qh * 8;
#pragma unroll
  for (int ip = 0; ip < 4; ++ip) {
    f32x4 v0, v1;
#pragma unroll
    for (int j = 0; j < 4; ++j) { v0[j] = out[ip][j] * 0.0625f; v1[j] = out[ip][j + 4] * 0.0625f; }
    *(f32x4*)(zb + (size_t)ip * 128) = v0;
    *(f32x4*)(zb + (size_t)ip * 128 + 4) = v1;
  }
}

// ================= fallback path (R2, proven): FIR-folded fused conv =================
__global__ void wprep36(const float* __restrict__ w, u16* __restrict__ Hm) {
  __shared__ float wl[4608];
  __shared__ float red[256];
  int o = blockIdx.x, t = threadIdx.x;
  const float* wo = w + (size_t)o * 4608;
  float s = 0.f;
  for (int j = t; j < 4608; j += 256) { float v = wo[j]; wl[j] = v; s += v * v; }
  red[t] = s;
  __syncthreads();
  for (int st = 128; st; st >>= 1) { if (t < st) red[t] += red[t + st]; __syncthreads(); }
  float demod = rsqrtf(red[0] * (1.0f / 4608.0f) + 1e-6f);
  float scale = demod * 0.014731391274719739f;
  const float F1[4] = {1.f, 3.f, 3.f, 1.f};
  for (int i = t; i < 512; i += 256) {
    float wm[9];
    for (int k = 0; k < 9; ++k) wm[k] = wl[i * 9 + k] * scale;
    for (int rp = 0; rp < 2; ++rp)
      for (int rq = 0; rq < 2; ++rq)
        for (int u = 0; u < 3; ++u)
          for (int v = 0; v < 3; ++v) {
            int s_ = 2 - 2 * u + rp, t_ = 2 - 2 * v + rq;
            float g = 0.f;
            for (int dy = 0; dy < 3; ++dy) {
              int a = dy + 1 - s_;
              if (a < 0 || a > 3) continue;
              for (int dx = 0; dx < 3; ++dx) {
                int b = dx + 1 - t_;
                if (b < 0 || b > 3) continue;
                g += wm[dy * 3 + dx] * (F1[a] * F1[b]);
              }
            }
            g *= 0.0625f;
            Hm[(size_t)((rp * 2 + rq) * 9 + u * 3 + v) * 131072 + (size_t)o * 512 + i] = f2bf(g);
          }
  }
}

__global__ __launch_bounds__(256) void conv_main(const u16* __restrict__ xp,
                                                 const u16* __restrict__ Hm,
                                                 float* __restrict__ z) {
  __shared__ __align__(16) float smemf[8448];
  u16* su = (u16*)smemf;
  int bid = blockIdx.x;
  int sub = bid & 7;
  int rp = sub >> 2;
  int o0 = (sub & 3) * 64;
  int mtile = bid >> 3;
  int n_img = mtile >> 5;
  int hp0 = (mtile & 31) * 2;
  int t = threadIdx.x;
  int wave = t >> 6, lane = t & 63;
  int wm0 = (wave & 1) * 64;
  int wn0 = (wave >> 1) * 32;
  int la = lane & 15;
  int ks = (lane >> 4) * 8;
  int rsel = t >> 2;
  int koff = (t & 3) * 8;
  f32x4 acc[2][4][2];
#pragma unroll
  for (int a = 0; a < 2; ++a)
#pragma unroll
    for (int b = 0; b < 4; ++b)
#pragma unroll
      for (int c = 0; c < 2; ++c)
        acc[a][b][c] = (f32x4){0.f, 0.f, 0.f, 0.f};
#pragma unroll 1
  for (int tap = 0; tap < 9; ++tap) {
    int du = tap / 3, dv = tap - du * 3;
    const u16* gA0 = xp + ((size_t)(n_img * 66 + hp0 + du) * 66 + dv) * 512;
    const u16* gB0 = Hm + (size_t)(rp * 18 + tap) * 131072 + (size_t)(o0 + rsel) * 512 + koff;
    const u16* gAr0 = gA0 + (size_t)rsel * 512 + koff;
    const u16* gAr1 = gA0 + (size_t)(66 + rsel) * 512 + koff;
#pragma unroll 1
    for (int kc = 0; kc < 16; ++kc) {
      int c0 = kc * 32;
      __syncthreads();
      gl_lds16(gAr0 + c0, su + wave * 512);
      gl_lds16(gAr1 + c0, su + 2048 + wave * 512);
      gl_lds16(gB0 + c0,              su + 4096 + wave * 512);
      gl_lds16(gB0 + 9 * 131072 + c0, su + 6144 + wave * 512);
      __syncthreads();
      bf16x8 af[4];
#pragma unroll
      for (int ti = 0; ti < 4; ++ti)
        af[ti] = *(const bf16x8*)(su + (wm0 + ti * 16 + la) * 32 + ks);
      bf16x8 bfr[2][2];
#pragma unroll
      for (int rqq = 0; rqq < 2; ++rqq)
#pragma unroll
        for (int tj = 0; tj < 2; ++tj)
          bfr[rqq][tj] = *(const bf16x8*)(su + 4096 + rqq * 2048 + (wn0 + tj * 16 + la) * 32 + ks);
#pragma unroll
      for (int rqq = 0; rqq < 2; ++rqq)
#pragma unroll
        for (int ti = 0; ti < 4; ++ti)
#pragma unroll
          for (int tj = 0; tj < 2; ++tj)
            acc[rqq][ti][tj] = __builtin_amdgcn_mfma_f32_16x16x32_bf16(
                af[ti], bfr[rqq][tj], acc[rqq][ti][tj], 0, 0, 0);
    }
  }
  __syncthreads();
  float* lws = smemf + wave * 2112;
  int p = 2 * (hp0 + (wave & 1)) + rp;
#pragma unroll
  for (int tj = 0; tj < 2; ++tj) {
#pragma unroll
    for (int rqq = 0; rqq < 2; ++rqq)
#pragma unroll
      for (int ti = 0; ti < 4; ++ti) {
        int wqb = ti * 16 + (lane >> 4) * 4;
        f32x4 v = acc[rqq][ti][tj];
#pragma unroll
        for (int r = 0; r < 4; ++r)
          lws[la * 132 + 2 * (wqb + r) + rqq] = v[r];
      }
    __syncthreads();
    int obase = o0 + wn0 + tj * 16;
#pragma unroll
    for (int c = 0; c < 8; ++c) {
      int idx = c * 64 + lane;
      int ol = idx >> 5, q4 = (idx & 31) * 4;
      f32x4 vv = *(const f32x4*)(lws + ol * 132 + q4);
      *(f32x4*)(z + (((size_t)n_img * 256 + obase + ol) * 128 + p) * 128 + q4) = vv;
    }
    __syncthreads();
  }
}

extern "C" void kernel_launch(void* const* d_in, const int* in_sizes, int n_in,
                              void* d_out, int out_size, void* d_ws, size_t ws_size,
                              hipStream_t stream) {
  const float* x = (const float*)d_in[0];
  const float* w = (const float*)d_in[1];
  float* z = (float*)d_out;
  u16* xp = (u16*)d_ws;

  if (ws_size >= WS_NEED) {
    u16* yb = (u16*)((char*)d_ws + XP_BYTES);
    u16* hy = (u16*)((char*)d_ws + HY_OFF);
    xprep<<<4096, 256, 0, stream>>>(x, xp);       // self-zeroing xp halos; no memset needed
    wprep9<<<256, 256, 0, stream>>>(w, hy);
    conv_y<<<1072, 512, 0, stream>>>(xp, hy, yb); // 8 img x 134 (class,mt,oh) tiles, XCD-pinned
    fir2<<<4096, 256, 0, stream>>>(yb, z);
  } else {
    u16* Hm = (u16*)((char*)d_ws + XP_BYTES);
    hipMemsetAsync(xp, 0, XP_BYTES, stream);
    xprep<<<4096, 256, 0, stream>>>(x, xp);
    wprep36<<<256, 256, 0, stream>>>(w, Hm);
    conv_main<<<2048, 256, 0, stream>>>(xp, Hm, z);
  }
}

// Round 4
// 322.145 us; speedup vs baseline: 1.0086x; 1.0086x over previous
//
#include <hip/hip_runtime.h>

typedef unsigned short u16;
typedef unsigned int u32;
typedef __attribute__((ext_vector_type(8))) short bf16x8;   // 8 bf16 = 4 VGPRs
typedef __attribute__((ext_vector_type(4))) float f32x4;

// ---- ws layout (planar path) ----
// xp bf16 [8][66][66][512] halo-padded NHWC : 35,684,352 B at 0
// yb: 8 u16 lead pad + 2048 chunks x 16776 u16 + 16 u16 trail = 68,714,544 B
//   per (img,o) chunk: plane0 (65x66) @0 sz4296 | plane1 (65x64) @4296 sz4160
//                      plane2 (64x66) @8456 sz4224 | plane3 (64x64) @12680 sz4096
// Hy bf16 [9][256][512] = 2,359,296 B
#define XP_BYTES 35684352
#define YB_BYTES 68714544
#define HY_OFF   (XP_BYTES + YB_BYTES)          // 104,398,896
#define WS_NEED  ((size_t)HY_OFF + 2359296)     // 106,758,192
#define CS 16776                                 // chunk stride (u16)

__device__ inline u16 f2bf(float f) {
  union { float f; unsigned u; } v; v.f = f;
  unsigned r = v.u + 0x7fffu + ((v.u >> 16) & 1u);
  return (u16)(r >> 16);
}

__device__ inline void gl_lds16(const u16* g, u16* l) {
  __builtin_amdgcn_global_load_lds(
      (const __attribute__((address_space(1))) unsigned int*)g,
      (__attribute__((address_space(3))) unsigned int*)l, 16, 0, 0);
}

// ---------------- x prep: f32 NCHW -> bf16 NHWC with 1-px zero halo (self-zeroing) ----------
__global__ void xprep(const float* __restrict__ x, u16* __restrict__ xp) {
  __shared__ float tile[64 * 65];
  int bid = blockIdx.x;
  int cc = bid & 7, h = (bid >> 3) & 63, n = bid >> 9;
  int c0 = cc * 64;
  int t = threadIdx.x;
  const float* xb = x + ((size_t)(n * 512 + c0) * 64 + h) * 64;
  for (int r = 0; r < 16; ++r) {
    int flat = r * 256 + t;
    int ci = flat >> 6, w = flat & 63;
    tile[w * 65 + ci] = xb[(size_t)ci * 4096 + w];
  }
  __syncthreads();
  u16* xpb = xp + ((size_t)(n * 66 + h + 1) * 66 + 1) * 512 + c0;
  for (int r = 0; r < 8; ++r) {
    int flat = r * 256 + t;
    int pr = flat & 31;
    int w = flat >> 5;
    int ci = pr * 2;
    float v0 = tile[w * 65 + ci], v1 = tile[w * 65 + ci + 1];
    unsigned pk = (unsigned)f2bf(v0) | ((unsigned)f2bf(v1) << 16);
    *(unsigned*)(xpb + (size_t)w * 512 + ci) = pk;
  }
  u16* rowbase = xp + ((size_t)(n * 66 + h + 1) * 66) * 512 + c0;
  if (t < 32) *(u32*)(rowbase + 2 * t) = 0u;
  else if (t < 64) *(u32*)(rowbase + (size_t)65 * 512 + 2 * (t - 32)) = 0u;
  if (h == 0) {
    u16* r0 = xp + ((size_t)(n * 66) * 66) * 512 + c0;
    for (int j = t; j < 2112; j += 256) {
      int col = j >> 5, wi = j & 31;
      *(u32*)(r0 + (size_t)col * 512 + 2 * wi) = 0u;
    }
  }
  if (h == 63) {
    u16* r65 = xp + ((size_t)(n * 66 + 65) * 66) * 512 + c0;
    for (int j = t; j < 2112; j += 256) {
      int col = j >> 5, wi = j & 31;
      *(u32*)(r65 + (size_t)col * 512 + 2 * wi) = 0u;
    }
  }
}

// ---------------- weight prep: modulate+demod, 9 conv-transpose tap planes ----------------
__global__ void wprep9(const float* __restrict__ w, u16* __restrict__ Hy) {
  __shared__ float wl[4608];
  __shared__ float red[256];
  int o = blockIdx.x, t = threadIdx.x;
  const float* wo = w + (size_t)o * 4608;
  float s = 0.f;
  for (int j = t; j < 4608; j += 256) { float v = wo[j]; wl[j] = v; s += v * v; }
  red[t] = s;
  __syncthreads();
  for (int st = 128; st; st >>= 1) { if (t < st) red[t] += red[t + st]; __syncthreads(); }
  float demod = rsqrtf(red[0] * (1.0f / 4608.0f) + 1e-6f);
  float scale = demod * 0.014731391274719739f;
  const int DY[9] = {0, 2, 0, 2, 0, 2, 1, 1, 1};
  const int DX[9] = {0, 0, 2, 2, 1, 1, 0, 2, 1};
  for (int i = t; i < 512; i += 256) {
#pragma unroll
    for (int pl = 0; pl < 9; ++pl) {
      float g = wl[i * 9 + DY[pl] * 3 + DX[pl]] * scale;
      Hy[(size_t)pl * 131072 + (size_t)o * 512 + i] = f2bf(g);
    }
  }
}

// ---------------- pass 1: conv-transpose y — BM256 x BN128, BK=32, 2-3 blocks/CU ----------
// 512 thr / 8 waves (2M x 4N); per-wave out 128m x 32o; 2 K-tiles per iter, 6 phases.
// LDS 48KiB: buf c at c*12288 u16: A halves at +0/+4096 (each 8KB), B at +8192 (8KB).
// PACKED 128-B-ROW LAYOUT (R4 fix for R3's 4-way conflicts): within each 8KB region,
//   logical index i (0..127 = m or o) + kchunk kc (0..3, 16B):
//     p = i & 63, hi = i >> 6, slot = (hi*4 + kc) ^ (p & 7), byte = p*128 + slot*16.
//   Rows are 128B -> XOR spans 8 slots -> per-octet ds_read_b128 covers all 32 banks
//   (R2's empirically conflict-free bank math). Stage side: gl_lds dest is linear
//   (lane t -> byte t*16 => p = t>>3, s = t&7); source pre-swizzled with the SAME
//   bijection: e = s^(p&7), hi = e>>2, c = e&3, i = hi*64+p (rule #21 both-sides).
// Phase plan (tiles t0=2it in buf0, t0+1 in buf1); stage issues: A=2x8KB halves, B=1x8KB:
//  p1 rd A-hi0,B-lo b0 | st A-h0(t+1)->b1 | q(0,0)
//  p2 rd B-hi b0       | st A-h1(t+1)->b1 | q(0,1)
//  p3 rd A-hi1 b0      | st B(t+2)->b0    | q(1,1)+q(1,0) ; WAITV1 [V0 last iter]
//  p4-p6 mirror on b1: st A(t+2)->b0 (p4,p5), B(t+3)->b1 (p6); WAITV1 at p6
// vmcnt ledger (loads/thread): prologue B(t0)1+A(t0)2+B(t1)1=4 -> WAITV1 leaves B(t1).
//  p3: 1+3 issued=4 -> WAITV1 retires B(t1)+A(t1) (needed p4), leaves B(t2).
//  p6: retires B(t2)+A(t2) (needed next p1), leaves B(t3). Last iter: WAITV0 at p3,
//  p4-6 stage nothing (tile>=NK guard) -> epilogue drained.
// WAR: every stage lands >=1 full barrier-pair after its region's last ds_read completes
//  (bf0/bf1 register-held; reads complete at WAITL before the closing barrier that
//  precedes the stage issue). MFMA pinned after lgkmcnt by sched_barrier(0) (rule #18).
#define BARR() __builtin_amdgcn_s_barrier()
#define WAITL() do { asm volatile("s_waitcnt lgkmcnt(0)" ::: "memory"); __builtin_amdgcn_sched_barrier(0); } while (0)
#define WAITV1() do { asm volatile("s_waitcnt vmcnt(1)" ::: "memory"); __builtin_amdgcn_sched_barrier(0); } while (0)
#define WAITV0() do { asm volatile("s_waitcnt vmcnt(0)" ::: "memory"); __builtin_amdgcn_sched_barrier(0); } while (0)

// read A fragment: sbA = 8KB half base (su + buf + wm*4096); p = ti*16+la; hi selects
// which 64-row subblock of the half; kchunk = grp.
__device__ __forceinline__ void rdA4(const u16* sbA, int la, int grp, int hi,
                                     bf16x8 af[4]) {
#pragma unroll
  for (int ti = 0; ti < 4; ++ti) {
    int p = ti * 16 + la;
    int slot = (hi * 4 + grp) ^ (p & 7);
    af[ti] = *(const bf16x8*)(sbA + p * 64 + slot * 8);
  }
}

__device__ __forceinline__ bf16x8 rdB1(const u16* sb, int r, int grp) {
  int p = r & 63, hi = r >> 6;
  int slot = (hi * 4 + grp) ^ (p & 7);
  return *(const bf16x8*)(sb + 8192 + p * 64 + slot * 8);
}

template <int MI, int NI>
__device__ __forceinline__ void qmfma4(const bf16x8 af[4], bf16x8 bf,
                                       f32x4 acc[8][2]) {
#pragma unroll
  for (int ti = 0; ti < 4; ++ti)
    acc[MI * 4 + ti][NI] = __builtin_amdgcn_mfma_f32_16x16x32_bf16(
        af[ti], bf, acc[MI * 4 + ti][NI], 0, 0, 0);
}

__device__ __forceinline__ void stA1(const u16* __restrict__ xp, u16* d,
                                     int tile, int NK, u32 a,
                                     u32 adj1, u32 adj2, u32 adj3) {
  if (tile < NK) {
    int tap = tile >> 4;
    u32 ko = (u32)((tile & 15) << 5);
    u32 adj = tap == 0 ? 0u : (tap == 1 ? adj1 : (tap == 2 ? adj2 : adj3));
    gl_lds16(xp + (a - adj + ko), d);
  }
}

__device__ __forceinline__ void stB1(const u16* __restrict__ hb, u16* d,
                                     int tile, int NK, u32 b) {
  if (tile < NK) {
    int tap = tile >> 4;
    u32 ko = (u32)((tile & 15) << 5);
    gl_lds16(hb + (size_t)tap * 131072 + (b + ko), d);
  }
}

__global__ __launch_bounds__(512, 4) void conv_y(const u16* __restrict__ xp,
                                                 const u16* __restrict__ Hy,
                                                 u16* __restrict__ yb) {
  __shared__ __align__(16) u16 su[24576];   // 48 KiB: 2 x (A 8192 u16 + B 4096 u16)

  int bid = blockIdx.x;
  int t = threadIdx.x;
  int wid = t >> 6, lane = t & 63;

  // img -> XCD pinned (8 imgs, 8 XCDs); heavy classes first within each img
  int img = bid & 7;
  int kk = bid >> 3;                       // 0..133
  int mt, oh, Wp, CNT, NTAP, PB, PO, STLIM;
  u32 adj1 = 0, adj2 = 0, adj3 = 0;        // (du*66+dv)*512 per tap (tap0 always 0)
  if (kk < 34)       { int k2 = kk;       mt = k2 >> 1; oh = k2 & 1; Wp = 66; CNT = 4290; NTAP = 4; PB = 0; PO = 0;     STLIM = 4296;
                       adj1 = 33792u; adj2 = 512u; adj3 = 34304u; }
  else if (kk < 68)  { int k2 = kk - 34;  mt = k2 >> 1; oh = k2 & 1; Wp = 64; CNT = 4160; NTAP = 2; PB = 4; PO = 4296;  STLIM = 4160;
                       adj1 = 33792u; }
  else if (kk < 102) { int k2 = kk - 68;  mt = k2 >> 1; oh = k2 & 1; Wp = 66; CNT = 4224; NTAP = 2; PB = 6; PO = 8456;  STLIM = 4224;
                       adj1 = 512u; }
  else               { int k2 = kk - 102; mt = k2 >> 1; oh = k2 & 1; Wp = 64; CNT = 4096; NTAP = 1; PB = 8; PO = 12680; STLIM = 4096; }

  int m0 = mt * 256;
  int o0 = oh * 128;
  int NK = NTAP * 16;                       // K-tiles of 32 ch
  int NITER = NTAP * 8;
  const u16* hb = Hy + (size_t)PB * 131072;

  int wm = wid >> 2, wn = wid & 3;          // 2M x 4N waves: wave = 128m x 32o
  int la = lane & 15, grp = lane >> 4;

  // staging mapping (packed layout, R4): lane t -> linear LDS byte t*16 within the 8KB
  // region; logical (i, kchunk) recovered via the slot bijection (see header comment).
  int sp = t >> 3;                          // phys row 0..63
  int se = (t & 7) ^ (sp & 7);              // e = hi*4 + c
  int shi = se >> 2, sc = se & 3;
  int sloc = shi * 64 + sp;                 // logical index 0..127 within region

  u32 gA0, gA1, gB;
  {
    int m = m0 + sloc;
    if (m > CNT - 1) m = CNT - 1;           // clamp (garbage compute, store-guarded)
    u32 a = (u32)m / (u32)Wp;
    u32 b = (u32)m - a * (u32)Wp;
    gA0 = (u32)(((img * 66 + a + 1) * 66 + (b + 1)) * 512 + sc * 8);
    m = m0 + 128 + sloc;
    if (m > CNT - 1) m = CNT - 1;
    a = (u32)m / (u32)Wp;
    b = (u32)m - a * (u32)Wp;
    gA1 = (u32)(((img * 66 + a + 1) * 66 + (b + 1)) * 512 + sc * 8);
    gB = (u32)((o0 + sloc) * 512 + sc * 8);
  }
  int ws = wid * 512;                       // per-wave staging slice (1 KiB)

  f32x4 acc[8][2];
#pragma unroll
  for (int i = 0; i < 8; ++i)
#pragma unroll
    for (int j = 0; j < 2; ++j) acc[i][j] = (f32x4){0.f, 0.f, 0.f, 0.f};

  // ---- prologue: B(t0), A(t0) both halves, B(t1); wait tile0, keep B(t1) in flight
  stB1(hb, su + 8192 + ws, 0, NK, gB);
  stA1(xp, su + 0 + ws, 0, NK, gA0, adj1, adj2, adj3);
  stA1(xp, su + 4096 + ws, 0, NK, gA1, adj1, adj2, adj3);
  stB1(hb, su + 20480 + ws, 1, NK, gB);
  WAITV1();
  BARR();

  bf16x8 af[4], bf0, bf1;

#pragma unroll 1
  for (int it = 0; it < NITER; ++it) {
    int t0 = 2 * it;
    bool more = (it + 1 < NITER);

    // ---- p1: buf0 q(0,0) | stage A-h0(t0+1) -> buf1
    rdA4(su + wm * 4096, la, grp, 0, af);
    bf0 = rdB1(su, wn * 32 + la, grp);
    stA1(xp, su + 12288 + ws, t0 + 1, NK, gA0, adj1, adj2, adj3);
    BARR(); WAITL();
    __builtin_amdgcn_s_setprio(1); qmfma4<0, 0>(af, bf0, acc); __builtin_amdgcn_s_setprio(0);
    BARR();
    // ---- p2: q(0,1) | stage A-h1(t0+1) -> buf1
    bf1 = rdB1(su, wn * 32 + 16 + la, grp);
    stA1(xp, su + 16384 + ws, t0 + 1, NK, gA1, adj1, adj2, adj3);
    BARR(); WAITL();
    __builtin_amdgcn_s_setprio(1); qmfma4<0, 1>(af, bf1, acc); __builtin_amdgcn_s_setprio(0);
    BARR();
    // ---- p3: q(1,1)+q(1,0) | stage B(t0+2) -> buf0 | counted vmcnt
    rdA4(su + wm * 4096, la, grp, 1, af);
    stB1(hb, su + 8192 + ws, t0 + 2, NK, gB);
    BARR(); WAITL();
    __builtin_amdgcn_s_setprio(1);
    qmfma4<1, 1>(af, bf1, acc); qmfma4<1, 0>(af, bf0, acc);
    __builtin_amdgcn_s_setprio(0);
    if (more) { WAITV1(); } else { WAITV0(); }
    BARR();
    // ---- p4: buf1 q(0,0) | stage A-h0(t0+2) -> buf0
    rdA4(su + 12288 + wm * 4096, la, grp, 0, af);
    bf0 = rdB1(su + 12288, wn * 32 + la, grp);
    stA1(xp, su + 0 + ws, t0 + 2, NK, gA0, adj1, adj2, adj3);
    BARR(); WAITL();
    __builtin_amdgcn_s_setprio(1); qmfma4<0, 0>(af, bf0, acc); __builtin_amdgcn_s_setprio(0);
    BARR();
    // ---- p5: q(0,1) | stage A-h1(t0+2) -> buf0
    bf1 = rdB1(su + 12288, wn * 32 + 16 + la, grp);
    stA1(xp, su + 4096 + ws, t0 + 2, NK, gA1, adj1, adj2, adj3);
    BARR(); WAITL();
    __builtin_amdgcn_s_setprio(1); qmfma4<0, 1>(af, bf1, acc); __builtin_amdgcn_s_setprio(0);
    BARR();
    // ---- p6: q(1,1)+q(1,0) | stage B(t0+3) -> buf1 | counted vmcnt
    rdA4(su + 12288 + wm * 4096, la, grp, 1, af);
    stB1(hb, su + 20480 + ws, t0 + 3, NK, gB);
    BARR(); WAITL();
    __builtin_amdgcn_s_setprio(1);
    qmfma4<1, 1>(af, bf1, acc); qmfma4<1, 0>(af, bf0, acc);
    __builtin_amdgcn_s_setprio(0);
    if (more) { WAITV1(); }
    BARR();
  }

  // ---- epilogue: two o-half rounds through LDS [64 o][256 m] u16 (32 KiB), XOR chunks
  WAITV0();          // defensive drain (ledger says already 0 here)
  __syncthreads();
  u16* ybp = yb + 8;
#pragma unroll 1
  for (int r = 0; r < 2; ++r) {
    if ((wn >> 1) == r) {
      int base_orl = (wn & 1) * 32;
#pragma unroll
      for (int nj = 0; nj < 2; ++nj) {
        int orl = base_orl + nj * 16 + la;
        int x7 = orl & 7;
#pragma unroll
        for (int mi8 = 0; mi8 < 8; ++mi8)
#pragma unroll
          for (int jp = 0; jp < 2; ++jp) {
            int ml = wm * 128 + mi8 * 16 + grp * 4 + jp * 2;
            u32 pk = (u32)f2bf(acc[mi8][nj][jp * 2]) |
                     ((u32)f2bf(acc[mi8][nj][jp * 2 + 1]) << 16);
            *(u32*)(su + orl * 256 + (((ml >> 3) ^ x7) * 8) + (ml & 7)) = pk;
          }
      }
    }
    __syncthreads();
    {
      int ol = t >> 3, s2 = t & 7;
      int og = o0 + r * 64 + ol;
      size_t gb = (size_t)(img * 256 + og) * CS + PO + m0;
      int x7 = ol & 7;
#pragma unroll
      for (int i = 0; i < 4; ++i) {
        int cidx = s2 * 4 + i;
        int m = cidx * 8;
        if (m0 + m < STLIM)
          *(bf16x8*)(ybp + gb + m) = *(const bf16x8*)(su + ol * 256 + ((cidx ^ x7) * 8));
      }
    }
    if (r == 0) __syncthreads();
  }
}

// ---------------- pass 2: depthwise FIR on planar y; thread = 4p x 8q z block ----------------
// Derivation (R4 bug fixed): z[p][q] = (1/16) sum f1[s]f1[t] y[p+s-1][q+t-1], f1={1,3,3,1}.
// y-phase row 2a+rp: s = 2a+rp-p+1. With a0 = 2*phb-1, hcol index la -> a = a0+la:
//   rp=0: ip0: 3h[1]+h[2] | ip1: h[1]+3h[2] | ip2: 3h[2]+h[3] | ip3: h[2]+3h[3]
//   rp=1: ip0: h[0]+3h[1] | ip1: 3h[1]+h[2] | ip2: h[1]+3h[2] | ip3: 3h[2]+h[3]
// cols with b0 = 4*qh-1, v index lb -> b = b0+lb, e = jq>>1:
//   rq=0: jq=2e: 3v[e+1]+v[e+2] | jq=2e+1: v[e+1]+3v[e+2]
//   rq=1: jq=2e: v[e]+3v[e+1]   | jq=2e+1: 3v[e+1]+v[e+2]
__global__ void fir2(const u16* __restrict__ yb, float* __restrict__ z) {
  int flat = blockIdx.x * 256 + threadIdx.x;
  int qh = flat & 15, phb = (flat >> 4) & 31, o = (flat >> 9) & 255, n = flat >> 17;
  const u16* cb = yb + 8 + (size_t)(n * 256 + o) * CS;
  int a0 = 2 * phb - 1;
  int b0 = 4 * qh - 1;

  float out[4][8];
#pragma unroll
  for (int i = 0; i < 4; ++i)
#pragma unroll
    for (int j = 0; j < 8; ++j) out[i][j] = 0.f;

  const int PO_[4] = {0, 4296, 8456, 12680};
  const int WP_[4] = {66, 64, 66, 64};
  const int HA_[4] = {65, 65, 64, 64};
  const int WB_[4] = {65, 64, 65, 64};

#pragma unroll
  for (int ph = 0; ph < 4; ++ph) {
    int rp = ph >> 1, rq = ph & 1;
    const u16* pb = cb + PO_[ph];
    float hcol[4][8];
#pragma unroll
    for (int la = 0; la < 4; ++la) {
      if (rp == 0 && la == 0) continue;          // row unused for rp=0 (folds at compile time)
      int ag = a0 + la;
      bool rv = (ag >= 0) && (ag < HA_[ph]);
      const u16* rb = pb + (ag * WP_[ph] + b0 - 1);   // even offset; pads keep it in d_ws
      u32 ls[4];
      ls[0] = *(const u32*)(rb);
      ls[1] = *(const u32*)(rb + 2);
      ls[2] = *(const u32*)(rb + 4);
      ls[3] = *(const u32*)(rb + 6);
      float v[6];
#pragma unroll
      for (int lb = 0; lb < 6; ++lb) {
        int jj = lb + 1;                          // rb[jj] = col b0-1+jj = b0+lb
        u32 w16 = (jj & 1) ? (ls[jj >> 1] >> 16) : (ls[jj >> 1] & 0xffffu);
        float fv = __uint_as_float(w16 << 16);
        int bg = b0 + lb;
        bool ok = rv && (bg >= 0) && (bg < WB_[ph]);
        v[lb] = ok ? fv : 0.f;
      }
#pragma unroll
      for (int e = 0; e < 4; ++e) {
        if (rq == 0) {
          hcol[la][2 * e]     = 3.f * v[e + 1] + v[e + 2];
          hcol[la][2 * e + 1] = v[e + 1] + 3.f * v[e + 2];
        } else {
          hcol[la][2 * e]     = v[e] + 3.f * v[e + 1];
          hcol[la][2 * e + 1] = 3.f * v[e + 1] + v[e + 2];
        }
      }
    }
#pragma unroll
    for (int jq = 0; jq < 8; ++jq) {
      if (rp == 0) {
        out[0][jq] += 3.f * hcol[1][jq] + hcol[2][jq];
        out[1][jq] += hcol[1][jq] + 3.f * hcol[2][jq];
        out[2][jq] += 3.f * hcol[2][jq] + hcol[3][jq];
        out[3][jq] += hcol[2][jq] + 3.f * hcol[3][jq];
      } else {
        out[0][jq] += hcol[0][jq] + 3.f * hcol[1][jq];
        out[1][jq] += 3.f * hcol[1][jq] + hcol[2][jq];
        out[2][jq] += hcol[1][jq] + 3.f * hcol[2][jq];
        out[3][jq] += 3.f * hcol[2][jq] + hcol[3][jq];
      }
    }
  }

  float* zb = z + ((size_t)(n * 256 + o) * 128 + phb * 4) * 128 + qh * 8;
#pragma unroll
  for (int ip = 0; ip < 4; ++ip) {
    f32x4 v0, v1;
#pragma unroll
    for (int j = 0; j < 4; ++j) { v0[j] = out[ip][j] * 0.0625f; v1[j] = out[ip][j + 4] * 0.0625f; }
    *(f32x4*)(zb + (size_t)ip * 128) = v0;
    *(f32x4*)(zb + (size_t)ip * 128 + 4) = v1;
  }
}

// ================= fallback path (R2, proven): FIR-folded fused conv =================
__global__ void wprep36(const float* __restrict__ w, u16* __restrict__ Hm) {
  __shared__ float wl[4608];
  __shared__ float red[256];
  int o = blockIdx.x, t = threadIdx.x;
  const float* wo = w + (size_t)o * 4608;
  float s = 0.f;
  for (int j = t; j < 4608; j += 256) { float v = wo[j]; wl[j] = v; s += v * v; }
  red[t] = s;
  __syncthreads();
  for (int st = 128; st; st >>= 1) { if (t < st) red[t] += red[t + st]; __syncthreads(); }
  float demod = rsqrtf(red[0] * (1.0f / 4608.0f) + 1e-6f);
  float scale = demod * 0.014731391274719739f;
  const float F1[4] = {1.f, 3.f, 3.f, 1.f};
  for (int i = t; i < 512; i += 256) {
    float wm[9];
    for (int k = 0; k < 9; ++k) wm[k] = wl[i * 9 + k] * scale;
    for (int rp = 0; rp < 2; ++rp)
      for (int rq = 0; rq < 2; ++rq)
        for (int u = 0; u < 3; ++u)
          for (int v = 0; v < 3; ++v) {
            int s_ = 2 - 2 * u + rp, t_ = 2 - 2 * v + rq;
            float g = 0.f;
            for (int dy = 0; dy < 3; ++dy) {
              int a = dy + 1 - s_;
              if (a < 0 || a > 3) continue;
              for (int dx = 0; dx < 3; ++dx) {
                int b = dx + 1 - t_;
                if (b < 0 || b > 3) continue;
                g += wm[dy * 3 + dx] * (F1[a] * F1[b]);
              }
            }
            g *= 0.0625f;
            Hm[(size_t)((rp * 2 + rq) * 9 + u * 3 + v) * 131072 + (size_t)o * 512 + i] = f2bf(g);
          }
  }
}

__global__ __launch_bounds__(256) void conv_main(const u16* __restrict__ xp,
                                                 const u16* __restrict__ Hm,
                                                 float* __restrict__ z) {
  __shared__ __align__(16) float smemf[8448];
  u16* su = (u16*)smemf;
  int bid = blockIdx.x;
  int sub = bid & 7;
  int rp = sub >> 2;
  int o0 = (sub & 3) * 64;
  int mtile = bid >> 3;
  int n_img = mtile >> 5;
  int hp0 = (mtile & 31) * 2;
  int t = threadIdx.x;
  int wave = t >> 6, lane = t & 63;
  int wm0 = (wave & 1) * 64;
  int wn0 = (wave >> 1) * 32;
  int la = lane & 15;
  int ks = (lane >> 4) * 8;
  int rsel = t >> 2;
  int koff = (t & 3) * 8;
  f32x4 acc[2][4][2];
#pragma unroll
  for (int a = 0; a < 2; ++a)
#pragma unroll
    for (int b = 0; b < 4; ++b)
#pragma unroll
      for (int c = 0; c < 2; ++c)
        acc[a][b][c] = (f32x4){0.f, 0.f, 0.f, 0.f};
#pragma unroll 1
  for (int tap = 0; tap < 9; ++tap) {
    int du = tap / 3, dv = tap - du * 3;
    const u16* gA0 = xp + ((size_t)(n_img * 66 + hp0 + du) * 66 + dv) * 512;
    const u16* gB0 = Hm + (size_t)(rp * 18 + tap) * 131072 + (size_t)(o0 + rsel) * 512 + koff;
    const u16* gAr0 = gA0 + (size_t)rsel * 512 + koff;
    const u16* gAr1 = gA0 + (size_t)(66 + rsel) * 512 + koff;
#pragma unroll 1
    for (int kc = 0; kc < 16; ++kc) {
      int c0 = kc * 32;
      __syncthreads();
      gl_lds16(gAr0 + c0, su + wave * 512);
      gl_lds16(gAr1 + c0, su + 2048 + wave * 512);
      gl_lds16(gB0 + c0,              su + 4096 + wave * 512);
      gl_lds16(gB0 + 9 * 131072 + c0, su + 6144 + wave * 512);
      __syncthreads();
      bf16x8 af[4];
#pragma unroll
      for (int ti = 0; ti < 4; ++ti)
        af[ti] = *(const bf16x8*)(su + (wm0 + ti * 16 + la) * 32 + ks);
      bf16x8 bfr[2][2];
#pragma unroll
      for (int rqq = 0; rqq < 2; ++rqq)
#pragma unroll
        for (int tj = 0; tj < 2; ++tj)
          bfr[rqq][tj] = *(const bf16x8*)(su + 4096 + rqq * 2048 + (wn0 + tj * 16 + la) * 32 + ks);
#pragma unroll
      for (int rqq = 0; rqq < 2; ++rqq)
#pragma unroll
        for (int ti = 0; ti < 4; ++ti)
#pragma unroll
          for (int tj = 0; tj < 2; ++tj)
            acc[rqq][ti][tj] = __builtin_amdgcn_mfma_f32_16x16x32_bf16(
                af[ti], bfr[rqq][tj], acc[rqq][ti][tj], 0, 0, 0);
    }
  }
  __syncthreads();
  float* lws = smemf + wave * 2112;
  int p = 2 * (hp0 + (wave & 1)) + rp;
#pragma unroll
  for (int tj = 0; tj < 2; ++tj) {
#pragma unroll
    for (int rqq = 0; rqq < 2; ++rqq)
#pragma unroll
      for (int ti = 0; ti < 4; ++ti) {
        int wqb = ti * 16 + (lane >> 4) * 4;
        f32x4 v = acc[rqq][ti][tj];
#pragma unroll
        for (int r = 0; r < 4; ++r)
          lws[la * 132 + 2 * (wqb + r) + rqq] = v[r];
      }
    __syncthreads();
    int obase = o0 + wn0 + tj * 16;
#pragma unroll
    for (int c = 0; c < 8; ++c) {
      int idx = c * 64 + lane;
      int ol = idx >> 5, q4 = (idx & 31) * 4;
      f32x4 vv = *(const f32x4*)(lws + ol * 132 + q4);
      *(f32x4*)(z + (((size_t)n_img * 256 + obase + ol) * 128 + p) * 128 + q4) = vv;
    }
    __syncthreads();
  }
}

extern "C" void kernel_launch(void* const* d_in, const int* in_sizes, int n_in,
                              void* d_out, int out_size, void* d_ws, size_t ws_size,
                              hipStream_t stream) {
  const float* x = (const float*)d_in[0];
  const float* w = (const float*)d_in[1];
  float* z = (float*)d_out;
  u16* xp = (u16*)d_ws;

  if (ws_size >= WS_NEED) {
    u16* yb = (u16*)((char*)d_ws + XP_BYTES);
    u16* hy = (u16*)((char*)d_ws + HY_OFF);
    xprep<<<4096, 256, 0, stream>>>(x, xp);       // self-zeroing xp halos; no memset needed
    wprep9<<<256, 256, 0, stream>>>(w, hy);
    conv_y<<<1072, 512, 0, stream>>>(xp, hy, yb); // 8 img x 134 (class,mt,oh) tiles, XCD-pinned
    fir2<<<4096, 256, 0, stream>>>(yb, z);
  } else {
    u16* Hm = (u16*)((char*)d_ws + XP_BYTES);
    hipMemsetAsync(xp, 0, XP_BYTES, stream);
    xprep<<<4096, 256, 0, stream>>>(x, xp);
    wprep36<<<256, 256, 0, stream>>>(w, Hm);
    conv_main<<<2048, 256, 0, stream>>>(xp, Hm, z);
  }
}

// Round 5
// 311.605 us; speedup vs baseline: 1.0427x; 1.0338x over previous
//
#include <hip/hip_runtime.h>

typedef unsigned short u16;
typedef unsigned int u32;
typedef __attribute__((ext_vector_type(8))) short bf16x8;   // 8 bf16 = 4 VGPRs
typedef __attribute__((ext_vector_type(4))) float f32x4;

// ---- ws layout (planar path) ----
// xp bf16 CHANNEL-PLANED [8 img][16 kc][66*66 rows][32 ch] : 35,684,352 B at 0
//   (plane stride 139,392 u16; img stride 2,230,272 u16) — R5 relayout so conv_y
//   staging reads are CONTIGUOUS (R4 scatter: 64 lines/wave-op; now 8, fully used).
// yb: 8 u16 lead pad + 2048 chunks x 16776 u16 + 16 u16 trail = 68,714,544 B
//   per (img,o) chunk: plane0 (65x66) @0 sz4296 | plane1 (65x64) @4296 sz4160
//                      plane2 (64x66) @8456 sz4224 | plane3 (64x64) @12680 sz4096
// Hy bf16 [9 pl][16 kc][256 o][32 ch] = 2,359,296 B (tap-plane stride 131,072 u16)
#define XP_BYTES 35684352
#define YB_BYTES 68714544
#define HY_OFF   (XP_BYTES + YB_BYTES)          // 104,398,896
#define WS_NEED  ((size_t)HY_OFF + 2359296)     // 106,758,192
#define CS 16776                                 // chunk stride (u16)

__device__ inline u16 f2bf(float f) {
  union { float f; unsigned u; } v; v.f = f;
  unsigned r = v.u + 0x7fffu + ((v.u >> 16) & 1u);
  return (u16)(r >> 16);
}

__device__ inline void gl_lds16(const u16* g, u16* l) {
  __builtin_amdgcn_global_load_lds(
      (const __attribute__((address_space(1))) unsigned int*)g,
      (__attribute__((address_space(3))) unsigned int*)l, 16, 0, 0);
}

// ---------------- x prep: f32 NCHW -> bf16 channel-planed with 1-px zero halo ----------
// plane kc holds ch [kc*32, kc*32+32); position (i,j) of padded 66x66 at row i*66+j.
__global__ void xprep(const float* __restrict__ x, u16* __restrict__ xp) {
  __shared__ float tile[64 * 65];
  int bid = blockIdx.x;
  int cc = bid & 7, h = (bid >> 3) & 63, n = bid >> 9;
  int c0 = cc * 64;
  int t = threadIdx.x;
  const float* xb = x + ((size_t)(n * 512 + c0) * 64 + h) * 64;
  for (int r = 0; r < 16; ++r) {
    int flat = r * 256 + t;
    int ci = flat >> 6, w = flat & 63;
    tile[w * 65 + ci] = xb[(size_t)ci * 4096 + w];
  }
  __syncthreads();
  // interior: position (h+1, w+1), channels c0+ci, c0+ci+1 (ci even -> same plane)
  for (int r = 0; r < 8; ++r) {
    int flat = r * 256 + t;
    int pr = flat & 31;
    int w = flat >> 5;
    int ci = pr * 2;
    float v0 = tile[w * 65 + ci], v1 = tile[w * 65 + ci + 1];
    unsigned pk = (unsigned)f2bf(v0) | ((unsigned)f2bf(v1) << 16);
    int kcabs = cc * 2 + (ci >> 5);
    int chl = ci & 31;
    u16* dst = xp + (size_t)(n * 16 + kcabs) * 139392 +
               (size_t)((h + 1) * 66 + (w + 1)) * 32 + chl;
    *(unsigned*)dst = pk;
  }
  // col halos: (h+1, 0) and (h+1, 65) for planes cc*2, cc*2+1 (32 u16 = 16 u32 each)
  if (t < 64) {
    int seg = t >> 4;                       // 0..3
    int colsel = (seg >> 1) ? 65 : 0;
    int pl = cc * 2 + (seg & 1);
    int ui = t & 15;
    u16* dst = xp + (size_t)(n * 16 + pl) * 139392 +
               (size_t)((h + 1) * 66 + colsel) * 32 + ui * 2;
    *(u32*)dst = 0u;
  }
  // row halos: padded rows 0 (h==0) and 65 (h==63): 66 cols x 2 planes x 16 u32
  if (h == 0 || h == 63) {
    int rowbase = (h == 0) ? 0 : 65 * 66;
    for (int j = t; j < 2112; j += 256) {
      int seg = j >> 4;                     // 0..131
      int ui = j & 15;
      int pl = cc * 2 + (seg & 1);
      int pos = seg >> 1;                   // 0..65
      u16* dst = xp + (size_t)(n * 16 + pl) * 139392 +
                 (size_t)(rowbase + pos) * 32 + ui * 2;
      *(u32*)dst = 0u;
    }
  }
}

// ---------------- weight prep: modulate+demod, 9 tap planes, channel-planed ----------------
__global__ void wprep9(const float* __restrict__ w, u16* __restrict__ Hy) {
  __shared__ float wl[4608];
  __shared__ float red[256];
  int o = blockIdx.x, t = threadIdx.x;
  const float* wo = w + (size_t)o * 4608;
  float s = 0.f;
  for (int j = t; j < 4608; j += 256) { float v = wo[j]; wl[j] = v; s += v * v; }
  red[t] = s;
  __syncthreads();
  for (int st = 128; st; st >>= 1) { if (t < st) red[t] += red[t + st]; __syncthreads(); }
  float demod = rsqrtf(red[0] * (1.0f / 4608.0f) + 1e-6f);
  float scale = demod * 0.014731391274719739f;
  const int DY[9] = {0, 2, 0, 2, 0, 2, 1, 1, 1};
  const int DX[9] = {0, 0, 2, 2, 1, 1, 0, 2, 1};
  for (int i = t; i < 512; i += 256) {
    int kc = i >> 5, il = i & 31;
#pragma unroll
    for (int pl = 0; pl < 9; ++pl) {
      float g = wl[i * 9 + DY[pl] * 3 + DX[pl]] * scale;
      Hy[(size_t)(pl * 16 + kc) * 8192 + (size_t)o * 32 + il] = f2bf(g);
    }
  }
}

// ---------------- pass 1: conv-transpose y — BM256 x BN128, BK=32 ----------
// IDENTICAL schedule/LDS/epilogue to R4 (6 phases, counted vmcnt, packed 128B-row LDS,
// 549K-conflict-verified). ONLY the global source layout/addressing changed (R5):
//   A K-tile (tap, kc) = xp plane (img, kc) rows [m0+reg*128 .. +127] x 32ch -> 8 KB
//   CONTIGUOUS; tap adjust = (du*66+dv)*32 u16 row shift. B K-tile = Hy plane
//   (PB+tap, kc) rows [o0 .. +127] -> 8 KB contiguous.
// Staging map (unchanged): thread t -> LDS byte t*16; sp=t>>3, e=(t&7)^(sp&7),
//   shi=e>>2, sc=e&3, sloc=shi*64+sp. Per wave-op source footprint: rows
//   [base+wid*8..+7] and [base+64+wid*8..+7] = 2 contiguous 512-B spans (8 lines,
//   100% consumed) vs R4's 64 sparse lines — the R4-measured invariant limiter.
// vmcnt ledger, WAR spacing, barrier uniformity: unchanged from R4 (audited).
#define BARR() __builtin_amdgcn_s_barrier()
#define WAITL() do { asm volatile("s_waitcnt lgkmcnt(0)" ::: "memory"); __builtin_amdgcn_sched_barrier(0); } while (0)
#define WAITV1() do { asm volatile("s_waitcnt vmcnt(1)" ::: "memory"); __builtin_amdgcn_sched_barrier(0); } while (0)
#define WAITV0() do { asm volatile("s_waitcnt vmcnt(0)" ::: "memory"); __builtin_amdgcn_sched_barrier(0); } while (0)

// read A fragment: sbA = 8KB region base (su + buf + wm*4096 u16); p = ti*16+la;
// hi selects 64-row subblock; kchunk = grp; slot = (hi*4+grp)^(p&7).
__device__ __forceinline__ void rdA4(const u16* sbA, int la, int grp, int hi,
                                     bf16x8 af[4]) {
#pragma unroll
  for (int ti = 0; ti < 4; ++ti) {
    int p = ti * 16 + la;
    int slot = (hi * 4 + grp) ^ (p & 7);
    af[ti] = *(const bf16x8*)(sbA + p * 64 + slot * 8);
  }
}

__device__ __forceinline__ bf16x8 rdB1(const u16* sb, int r, int grp) {
  int p = r & 63, hi = r >> 6;
  int slot = (hi * 4 + grp) ^ (p & 7);
  return *(const bf16x8*)(sb + 8192 + p * 64 + slot * 8);
}

template <int MI, int NI>
__device__ __forceinline__ void qmfma4(const bf16x8 af[4], bf16x8 bf,
                                       f32x4 acc[8][2]) {
#pragma unroll
  for (int ti = 0; ti < 4; ++ti)
    acc[MI * 4 + ti][NI] = __builtin_amdgcn_mfma_f32_16x16x32_bf16(
        af[ti], bf, acc[MI * 4 + ti][NI], 0, 0, 0);
}

__device__ __forceinline__ void stA1(const u16* __restrict__ xp, u16* d,
                                     int tile, int NK, u32 a,
                                     u32 adj1, u32 adj2, u32 adj3) {
  if (tile < NK) {
    int tap = tile >> 4;
    u32 ko = (u32)((tile & 15) * 139392);   // kc plane stride (u16)
    u32 adj = tap == 0 ? 0u : (tap == 1 ? adj1 : (tap == 2 ? adj2 : adj3));
    gl_lds16(xp + (a + ko - adj), d);
  }
}

__device__ __forceinline__ void stB1(const u16* __restrict__ hb, u16* d,
                                     int tile, int NK, u32 b) {
  if (tile < NK) {
    int tap = tile >> 4;
    u32 ko = (u32)(tap * 131072 + (tile & 15) * 8192);
    gl_lds16(hb + (b + ko), d);
  }
}

__global__ __launch_bounds__(512, 4) void conv_y(const u16* __restrict__ xp,
                                                 const u16* __restrict__ Hy,
                                                 u16* __restrict__ yb) {
  __shared__ __align__(16) u16 su[24576];   // 48 KiB: 2 x (A 8192 u16 + B 4096 u16)

  int bid = blockIdx.x;
  int t = threadIdx.x;
  int wid = t >> 6, lane = t & 63;

  // img -> XCD pinned (8 imgs, 8 XCDs); heavy classes first within each img
  int img = bid & 7;
  int kk = bid >> 3;                       // 0..133
  int mt, oh, Wp, CNT, NTAP, PB, PO, STLIM;
  u32 adj1 = 0, adj2 = 0, adj3 = 0;        // (du*66+dv)*32 u16 per tap (tap0 always 0)
  if (kk < 34)       { int k2 = kk;       mt = k2 >> 1; oh = k2 & 1; Wp = 66; CNT = 4290; NTAP = 4; PB = 0; PO = 0;     STLIM = 4296;
                       adj1 = 2112u; adj2 = 32u; adj3 = 2144u; }
  else if (kk < 68)  { int k2 = kk - 34;  mt = k2 >> 1; oh = k2 & 1; Wp = 64; CNT = 4160; NTAP = 2; PB = 4; PO = 4296;  STLIM = 4160;
                       adj1 = 2112u; }
  else if (kk < 102) { int k2 = kk - 68;  mt = k2 >> 1; oh = k2 & 1; Wp = 66; CNT = 4224; NTAP = 2; PB = 6; PO = 8456;  STLIM = 4224;
                       adj1 = 32u; }
  else               { int k2 = kk - 102; mt = k2 >> 1; oh = k2 & 1; Wp = 64; CNT = 4096; NTAP = 1; PB = 8; PO = 12680; STLIM = 4096; }

  int m0 = mt * 256;
  int o0 = oh * 128;
  int NK = NTAP * 16;                       // K-tiles of 32 ch
  int NITER = NTAP * 8;
  const u16* hb = Hy + (size_t)PB * 131072;

  int wm = wid >> 2, wn = wid & 3;          // 2M x 4N waves: wave = 128m x 32o
  int la = lane & 15, grp = lane >> 4;

  // staging mapping (unchanged from R4): thread t -> LDS byte t*16 in region;
  // logical (sloc, sc) via the slot bijection.
  int sp = t >> 3;                          // phys row 0..63
  int se = (t & 7) ^ (sp & 7);              // e = hi*4 + c
  int shi = se >> 2, sc = se & 3;
  int sloc = shi * 64 + sp;                 // logical index 0..127 within region

  u32 gA0, gA1, gB;
  {
    u32 ib = (u32)img * 2230272u;           // img plane-base (u16)
    int m = m0 + sloc;
    if (m > CNT - 1) m = CNT - 1;           // clamp (garbage compute, store-guarded;
    u32 a = (u32)m / (u32)Wp;               //  class-edge wraps feed only dead cols)
    u32 b = (u32)m - a * (u32)Wp;
    gA0 = ib + ((a + 1) * 66 + (b + 1)) * 32 + sc * 8;
    m = m0 + 128 + sloc;
    if (m > CNT - 1) m = CNT - 1;
    a = (u32)m / (u32)Wp;
    b = (u32)m - a * (u32)Wp;
    gA1 = ib + ((a + 1) * 66 + (b + 1)) * 32 + sc * 8;
    gB = (u32)((o0 + sloc) * 32 + sc * 8);
  }
  int ws = wid * 512;                       // per-wave staging slice (1 KiB)

  f32x4 acc[8][2];
#pragma unroll
  for (int i = 0; i < 8; ++i)
#pragma unroll
    for (int j = 0; j < 2; ++j) acc[i][j] = (f32x4){0.f, 0.f, 0.f, 0.f};

  // ---- prologue: B(t0), A(t0) both halves, B(t1); wait tile0, keep B(t1) in flight
  stB1(hb, su + 8192 + ws, 0, NK, gB);
  stA1(xp, su + 0 + ws, 0, NK, gA0, adj1, adj2, adj3);
  stA1(xp, su + 4096 + ws, 0, NK, gA1, adj1, adj2, adj3);
  stB1(hb, su + 20480 + ws, 1, NK, gB);
  WAITV1();
  BARR();

  bf16x8 af[4], bf0, bf1;

#pragma unroll 1
  for (int it = 0; it < NITER; ++it) {
    int t0 = 2 * it;
    bool more = (it + 1 < NITER);

    // ---- p1: buf0 q(0,0) | stage A-h0(t0+1) -> buf1
    rdA4(su + wm * 4096, la, grp, 0, af);
    bf0 = rdB1(su, wn * 32 + la, grp);
    stA1(xp, su + 12288 + ws, t0 + 1, NK, gA0, adj1, adj2, adj3);
    BARR(); WAITL();
    __builtin_amdgcn_s_setprio(1); qmfma4<0, 0>(af, bf0, acc); __builtin_amdgcn_s_setprio(0);
    BARR();
    // ---- p2: q(0,1) | stage A-h1(t0+1) -> buf1
    bf1 = rdB1(su, wn * 32 + 16 + la, grp);
    stA1(xp, su + 16384 + ws, t0 + 1, NK, gA1, adj1, adj2, adj3);
    BARR(); WAITL();
    __builtin_amdgcn_s_setprio(1); qmfma4<0, 1>(af, bf1, acc); __builtin_amdgcn_s_setprio(0);
    BARR();
    // ---- p3: q(1,1)+q(1,0) | stage B(t0+2) -> buf0 | counted vmcnt
    rdA4(su + wm * 4096, la, grp, 1, af);
    stB1(hb, su + 8192 + ws, t0 + 2, NK, gB);
    BARR(); WAITL();
    __builtin_amdgcn_s_setprio(1);
    qmfma4<1, 1>(af, bf1, acc); qmfma4<1, 0>(af, bf0, acc);
    __builtin_amdgcn_s_setprio(0);
    if (more) { WAITV1(); } else { WAITV0(); }
    BARR();
    // ---- p4: buf1 q(0,0) | stage A-h0(t0+2) -> buf0
    rdA4(su + 12288 + wm * 4096, la, grp, 0, af);
    bf0 = rdB1(su + 12288, wn * 32 + la, grp);
    stA1(xp, su + 0 + ws, t0 + 2, NK, gA0, adj1, adj2, adj3);
    BARR(); WAITL();
    __builtin_amdgcn_s_setprio(1); qmfma4<0, 0>(af, bf0, acc); __builtin_amdgcn_s_setprio(0);
    BARR();
    // ---- p5: q(0,1) | stage A-h1(t0+2) -> buf0
    bf1 = rdB1(su + 12288, wn * 32 + 16 + la, grp);
    stA1(xp, su + 4096 + ws, t0 + 2, NK, gA1, adj1, adj2, adj3);
    BARR(); WAITL();
    __builtin_amdgcn_s_setprio(1); qmfma4<0, 1>(af, bf1, acc); __builtin_amdgcn_s_setprio(0);
    BARR();
    // ---- p6: q(1,1)+q(1,0) | stage B(t0+3) -> buf1 | counted vmcnt
    rdA4(su + 12288 + wm * 4096, la, grp, 1, af);
    stB1(hb, su + 20480 + ws, t0 + 3, NK, gB);
    BARR(); WAITL();
    __builtin_amdgcn_s_setprio(1);
    qmfma4<1, 1>(af, bf1, acc); qmfma4<1, 0>(af, bf0, acc);
    __builtin_amdgcn_s_setprio(0);
    if (more) { WAITV1(); }
    BARR();
  }

  // ---- epilogue: two o-half rounds through LDS [64 o][256 m] u16 (32 KiB), XOR chunks
  WAITV0();          // defensive drain (ledger says already 0 here)
  __syncthreads();
  u16* ybp = yb + 8;
#pragma unroll 1
  for (int r = 0; r < 2; ++r) {
    if ((wn >> 1) == r) {
      int base_orl = (wn & 1) * 32;
#pragma unroll
      for (int nj = 0; nj < 2; ++nj) {
        int orl = base_orl + nj * 16 + la;
        int x7 = orl & 7;
#pragma unroll
        for (int mi8 = 0; mi8 < 8; ++mi8)
#pragma unroll
          for (int jp = 0; jp < 2; ++jp) {
            int ml = wm * 128 + mi8 * 16 + grp * 4 + jp * 2;
            u32 pk = (u32)f2bf(acc[mi8][nj][jp * 2]) |
                     ((u32)f2bf(acc[mi8][nj][jp * 2 + 1]) << 16);
            *(u32*)(su + orl * 256 + (((ml >> 3) ^ x7) * 8) + (ml & 7)) = pk;
          }
      }
    }
    __syncthreads();
    {
      int ol = t >> 3, s2 = t & 7;
      int og = o0 + r * 64 + ol;
      size_t gb = (size_t)(img * 256 + og) * CS + PO + m0;
      int x7 = ol & 7;
#pragma unroll
      for (int i = 0; i < 4; ++i) {
        int cidx = s2 * 4 + i;
        int m = cidx * 8;
        if (m0 + m < STLIM)
          *(bf16x8*)(ybp + gb + m) = *(const bf16x8*)(su + ol * 256 + ((cidx ^ x7) * 8));
      }
    }
    if (r == 0) __syncthreads();
  }
}

// ---------------- pass 2: depthwise FIR on planar y; thread = 4p x 8q z block ----------------
// Derivation: z[p][q] = (1/16) sum f1[s]f1[t] y[p+s-1][q+t-1], f1={1,3,3,1}.
// y-phase row 2a+rp: s = 2a+rp-p+1. With a0 = 2*phb-1, hcol index la -> a = a0+la:
//   rp=0: ip0: 3h[1]+h[2] | ip1: h[1]+3h[2] | ip2: 3h[2]+h[3] | ip3: h[2]+3h[3]
//   rp=1: ip0: h[0]+3h[1] | ip1: 3h[1]+h[2] | ip2: h[1]+3h[2] | ip3: 3h[2]+h[3]
// cols with b0 = 4*qh-1, v index lb -> b = b0+lb, e = jq>>1:
//   rq=0: jq=2e: 3v[e+1]+v[e+2] | jq=2e+1: v[e+1]+3v[e+2]
//   rq=1: jq=2e: v[e]+3v[e+1]   | jq=2e+1: 3v[e+1]+v[e+2]
__global__ void fir2(const u16* __restrict__ yb, float* __restrict__ z) {
  int flat = blockIdx.x * 256 + threadIdx.x;
  int qh = flat & 15, phb = (flat >> 4) & 31, o = (flat >> 9) & 255, n = flat >> 17;
  const u16* cb = yb + 8 + (size_t)(n * 256 + o) * CS;
  int a0 = 2 * phb - 1;
  int b0 = 4 * qh - 1;

  float out[4][8];
#pragma unroll
  for (int i = 0; i < 4; ++i)
#pragma unroll
    for (int j = 0; j < 8; ++j) out[i][j] = 0.f;

  const int PO_[4] = {0, 4296, 8456, 12680};
  const int WP_[4] = {66, 64, 66, 64};
  const int HA_[4] = {65, 65, 64, 64};
  const int WB_[4] = {65, 64, 65, 64};

#pragma unroll
  for (int ph = 0; ph < 4; ++ph) {
    int rp = ph >> 1, rq = ph & 1;
    const u16* pb = cb + PO_[ph];
    float hcol[4][8];
#pragma unroll
    for (int la = 0; la < 4; ++la) {
      if (rp == 0 && la == 0) continue;          // row unused for rp=0 (folds at compile time)
      int ag = a0 + la;
      bool rv = (ag >= 0) && (ag < HA_[ph]);
      const u16* rb = pb + (ag * WP_[ph] + b0 - 1);   // even offset; pads keep it in d_ws
      u32 ls[4];
      ls[0] = *(const u32*)(rb);
      ls[1] = *(const u32*)(rb + 2);
      ls[2] = *(const u32*)(rb + 4);
      ls[3] = *(const u32*)(rb + 6);
      float v[6];
#pragma unroll
      for (int lb = 0; lb < 6; ++lb) {
        int jj = lb + 1;                          // rb[jj] = col b0-1+jj = b0+lb
        u32 w16 = (jj & 1) ? (ls[jj >> 1] >> 16) : (ls[jj >> 1] & 0xffffu);
        float fv = __uint_as_float(w16 << 16);
        int bg = b0 + lb;
        bool ok = rv && (bg >= 0) && (bg < WB_[ph]);
        v[lb] = ok ? fv : 0.f;
      }
#pragma unroll
      for (int e = 0; e < 4; ++e) {
        if (rq == 0) {
          hcol[la][2 * e]     = 3.f * v[e + 1] + v[e + 2];
          hcol[la][2 * e + 1] = v[e + 1] + 3.f * v[e + 2];
        } else {
          hcol[la][2 * e]     = v[e] + 3.f * v[e + 1];
          hcol[la][2 * e + 1] = 3.f * v[e + 1] + v[e + 2];
        }
      }
    }
#pragma unroll
    for (int jq = 0; jq < 8; ++jq) {
      if (rp == 0) {
        out[0][jq] += 3.f * hcol[1][jq] + hcol[2][jq];
        out[1][jq] += hcol[1][jq] + 3.f * hcol[2][jq];
        out[2][jq] += 3.f * hcol[2][jq] + hcol[3][jq];
        out[3][jq] += hcol[2][jq] + 3.f * hcol[3][jq];
      } else {
        out[0][jq] += hcol[0][jq] + 3.f * hcol[1][jq];
        out[1][jq] += 3.f * hcol[1][jq] + hcol[2][jq];
        out[2][jq] += hcol[1][jq] + 3.f * hcol[2][jq];
        out[3][jq] += 3.f * hcol[2][jq] + hcol[3][jq];
      }
    }
  }

  float* zb = z + ((size_t)(n * 256 + o) * 128 + phb * 4) * 128 + qh * 8;
#pragma unroll
  for (int ip = 0; ip < 4; ++ip) {
    f32x4 v0, v1;
#pragma unroll
    for (int j = 0; j < 4; ++j) { v0[j] = out[ip][j] * 0.0625f; v1[j] = out[ip][j + 4] * 0.0625f; }
    *(f32x4*)(zb + (size_t)ip * 128) = v0;
    *(f32x4*)(zb + (size_t)ip * 128 + 4) = v1;
  }
}

// ================= fallback path (R2, proven): FIR-folded fused conv =================
// Uses OLD flat NHWC xp layout -> has its own xprep_flat.
__global__ void xprep_flat(const float* __restrict__ x, u16* __restrict__ xp) {
  __shared__ float tile[64 * 65];
  int bid = blockIdx.x;
  int cc = bid & 7, h = (bid >> 3) & 63, n = bid >> 9;
  int c0 = cc * 64;
  int t = threadIdx.x;
  const float* xb = x + ((size_t)(n * 512 + c0) * 64 + h) * 64;
  for (int r = 0; r < 16; ++r) {
    int flat = r * 256 + t;
    int ci = flat >> 6, w = flat & 63;
    tile[w * 65 + ci] = xb[(size_t)ci * 4096 + w];
  }
  __syncthreads();
  u16* xpb = xp + ((size_t)(n * 66 + h + 1) * 66 + 1) * 512 + c0;
  for (int r = 0; r < 8; ++r) {
    int flat = r * 256 + t;
    int pr = flat & 31;
    int w = flat >> 5;
    int ci = pr * 2;
    float v0 = tile[w * 65 + ci], v1 = tile[w * 65 + ci + 1];
    unsigned pk = (unsigned)f2bf(v0) | ((unsigned)f2bf(v1) << 16);
    *(unsigned*)(xpb + (size_t)w * 512 + ci) = pk;
  }
  u16* rowbase = xp + ((size_t)(n * 66 + h + 1) * 66) * 512 + c0;
  if (t < 32) *(u32*)(rowbase + 2 * t) = 0u;
  else if (t < 64) *(u32*)(rowbase + (size_t)65 * 512 + 2 * (t - 32)) = 0u;
  if (h == 0) {
    u16* r0 = xp + ((size_t)(n * 66) * 66) * 512 + c0;
    for (int j = t; j < 2112; j += 256) {
      int col = j >> 5, wi = j & 31;
      *(u32*)(r0 + (size_t)col * 512 + 2 * wi) = 0u;
    }
  }
  if (h == 63) {
    u16* r65 = xp + ((size_t)(n * 66 + 65) * 66) * 512 + c0;
    for (int j = t; j < 2112; j += 256) {
      int col = j >> 5, wi = j & 31;
      *(u32*)(r65 + (size_t)col * 512 + 2 * wi) = 0u;
    }
  }
}

__global__ void wprep36(const float* __restrict__ w, u16* __restrict__ Hm) {
  __shared__ float wl[4608];
  __shared__ float red[256];
  int o = blockIdx.x, t = threadIdx.x;
  const float* wo = w + (size_t)o * 4608;
  float s = 0.f;
  for (int j = t; j < 4608; j += 256) { float v = wo[j]; wl[j] = v; s += v * v; }
  red[t] = s;
  __syncthreads();
  for (int st = 128; st; st >>= 1) { if (t < st) red[t] += red[t + st]; __syncthreads(); }
  float demod = rsqrtf(red[0] * (1.0f / 4608.0f) + 1e-6f);
  float scale = demod * 0.014731391274719739f;
  const float F1[4] = {1.f, 3.f, 3.f, 1.f};
  for (int i = t; i < 512; i += 256) {
    float wm[9];
    for (int k = 0; k < 9; ++k) wm[k] = wl[i * 9 + k] * scale;
    for (int rp = 0; rp < 2; ++rp)
      for (int rq = 0; rq < 2; ++rq)
        for (int u = 0; u < 3; ++u)
          for (int v = 0; v < 3; ++v) {
            int s_ = 2 - 2 * u + rp, t_ = 2 - 2 * v + rq;
            float g = 0.f;
            for (int dy = 0; dy < 3; ++dy) {
              int a = dy + 1 - s_;
              if (a < 0 || a > 3) continue;
              for (int dx = 0; dx < 3; ++dx) {
                int b = dx + 1 - t_;
                if (b < 0 || b > 3) continue;
                g += wm[dy * 3 + dx] * (F1[a] * F1[b]);
              }
            }
            g *= 0.0625f;
            Hm[(size_t)((rp * 2 + rq) * 9 + u * 3 + v) * 131072 + (size_t)o * 512 + i] = f2bf(g);
          }
  }
}

__global__ __launch_bounds__(256) void conv_main(const u16* __restrict__ xp,
                                                 const u16* __restrict__ Hm,
                                                 float* __restrict__ z) {
  __shared__ __align__(16) float smemf[8448];
  u16* su = (u16*)smemf;
  int bid = blockIdx.x;
  int sub = bid & 7;
  int rp = sub >> 2;
  int o0 = (sub & 3) * 64;
  int mtile = bid >> 3;
  int n_img = mtile >> 5;
  int hp0 = (mtile & 31) * 2;
  int t = threadIdx.x;
  int wave = t >> 6, lane = t & 63;
  int wm0 = (wave & 1) * 64;
  int wn0 = (wave >> 1) * 32;
  int la = lane & 15;
  int ks = (lane >> 4) * 8;
  int rsel = t >> 2;
  int koff = (t & 3) * 8;
  f32x4 acc[2][4][2];
#pragma unroll
  for (int a = 0; a < 2; ++a)
#pragma unroll
    for (int b = 0; b < 4; ++b)
#pragma unroll
      for (int c = 0; c < 2; ++c)
        acc[a][b][c] = (f32x4){0.f, 0.f, 0.f, 0.f};
#pragma unroll 1
  for (int tap = 0; tap < 9; ++tap) {
    int du = tap / 3, dv = tap - du * 3;
    const u16* gA0 = xp + ((size_t)(n_img * 66 + hp0 + du) * 66 + dv) * 512;
    const u16* gB0 = Hm + (size_t)(rp * 18 + tap) * 131072 + (size_t)(o0 + rsel) * 512 + koff;
    const u16* gAr0 = gA0 + (size_t)rsel * 512 + koff;
    const u16* gAr1 = gA0 + (size_t)(66 + rsel) * 512 + koff;
#pragma unroll 1
    for (int kc = 0; kc < 16; ++kc) {
      int c0 = kc * 32;
      __syncthreads();
      gl_lds16(gAr0 + c0, su + wave * 512);
      gl_lds16(gAr1 + c0, su + 2048 + wave * 512);
      gl_lds16(gB0 + c0,              su + 4096 + wave * 512);
      gl_lds16(gB0 + 9 * 131072 + c0, su + 6144 + wave * 512);
      __syncthreads();
      bf16x8 af[4];
#pragma unroll
      for (int ti = 0; ti < 4; ++ti)
        af[ti] = *(const bf16x8*)(su + (wm0 + ti * 16 + la) * 32 + ks);
      bf16x8 bfr[2][2];
#pragma unroll
      for (int rqq = 0; rqq < 2; ++rqq)
#pragma unroll
        for (int tj = 0; tj < 2; ++tj)
          bfr[rqq][tj] = *(const bf16x8*)(su + 4096 + rqq * 2048 + (wn0 + tj * 16 + la) * 32 + ks);
#pragma unroll
      for (int rqq = 0; rqq < 2; ++rqq)
#pragma unroll
        for (int ti = 0; ti < 4; ++ti)
#pragma unroll
          for (int tj = 0; tj < 2; ++tj)
            acc[rqq][ti][tj] = __builtin_amdgcn_mfma_f32_16x16x32_bf16(
                af[ti], bfr[rqq][tj], acc[rqq][ti][tj], 0, 0, 0);
    }
  }
  __syncthreads();
  float* lws = smemf + wave * 2112;
  int p = 2 * (hp0 + (wave & 1)) + rp;
#pragma unroll
  for (int tj = 0; tj < 2; ++tj) {
#pragma unroll
    for (int rqq = 0; rqq < 2; ++rqq)
#pragma unroll
      for (int ti = 0; ti < 4; ++ti) {
        int wqb = ti * 16 + (lane >> 4) * 4;
        f32x4 v = acc[rqq][ti][tj];
#pragma unroll
        for (int r = 0; r < 4; ++r)
          lws[la * 132 + 2 * (wqb + r) + rqq] = v[r];
      }
    __syncthreads();
    int obase = o0 + wn0 + tj * 16;
#pragma unroll
    for (int c = 0; c < 8; ++c) {
      int idx = c * 64 + lane;
      int ol = idx >> 5, q4 = (idx & 31) * 4;
      f32x4 vv = *(const f32x4*)(lws + ol * 132 + q4);
      *(f32x4*)(z + (((size_t)n_img * 256 + obase + ol) * 128 + p) * 128 + q4) = vv;
    }
    __syncthreads();
  }
}

extern "C" void kernel_launch(void* const* d_in, const int* in_sizes, int n_in,
                              void* d_out, int out_size, void* d_ws, size_t ws_size,
                              hipStream_t stream) {
  const float* x = (const float*)d_in[0];
  const float* w = (const float*)d_in[1];
  float* z = (float*)d_out;
  u16* xp = (u16*)d_ws;

  if (ws_size >= WS_NEED) {
    u16* yb = (u16*)((char*)d_ws + XP_BYTES);
    u16* hy = (u16*)((char*)d_ws + HY_OFF);
    xprep<<<4096, 256, 0, stream>>>(x, xp);       // channel-planed; self-zeroing halos
    wprep9<<<256, 256, 0, stream>>>(w, hy);
    conv_y<<<1072, 512, 0, stream>>>(xp, hy, yb); // 8 img x 134 tiles, XCD-pinned
    fir2<<<4096, 256, 0, stream>>>(yb, z);
  } else {
    u16* Hm = (u16*)((char*)d_ws + XP_BYTES);
    hipMemsetAsync(xp, 0, XP_BYTES, stream);
    xprep_flat<<<4096, 256, 0, stream>>>(x, xp);
    wprep36<<<256, 256, 0, stream>>>(w, Hm);
    conv_main<<<2048, 256, 0, stream>>>(xp, Hm, z);
  }
}